// Round 5
// baseline (12036.217 us; speedup 1.0000x reference)
//
#include <hip/hip_runtime.h>
#include <cstdint>
#include <cstddef>

// ---------------------------------------------------------------------------
// CTC-CRF BLSTM pipeline for MI355X.  B=64 T=1024 IDIM=120 HDIM=320 K=72
// den == 0 analytically; batch sort is a no-op under the batch mean. Skipped.
//
// Time-chunked (CT=128, 8 chunks/layer), ~223 MB workspace.
// Scan step (R5): 3-phase wave-specialized pipeline.
//   waves 0-3 (A): dot over OWN-half k (h produced locally) -- runs while
//   waves 4-7 (B): poll partner's tagged u64 words (RTT hidden behind A-dot),
//   then B dots partner-half k while A flushes xnext from an LDS ring
//   (kills per-step scattered-store vmcnt drain). Phase 3: gates (tid<160).
//   Publish = u64 atomicExch at phase-1 top (drain overlaps phase-1).
// CTC (R5): one wave/batch, 4 alpha/lane in registers, shfl_up neighbors,
//   depth-2 em prefetch, no barriers in the t-loop.
// ---------------------------------------------------------------------------

typedef _Float16 f16;
typedef _Float16 h2v   __attribute__((ext_vector_type(2)));
typedef _Float16 f16x8 __attribute__((ext_vector_type(8)));
typedef float    f32x4 __attribute__((ext_vector_type(4)));
typedef unsigned long long u64;

#define NEGF (-1e30f)
#define CT 128

__device__ __forceinline__ float dot2f(h2v a, h2v b, float c) {
#if __has_builtin(__builtin_amdgcn_fdot2)
  return __builtin_amdgcn_fdot2(a, b, c, false);
#else
  return c + (float)a.x * (float)b.x + (float)a.y * (float)b.y;
#endif
}

__device__ __forceinline__ void stage16(f16* lds, const f16* g) {
#if __has_builtin(__builtin_amdgcn_global_load_lds)
  __builtin_amdgcn_global_load_lds(
      (const __attribute__((address_space(1))) uint32_t*)g,
      (__attribute__((address_space(3))) uint32_t*)lds, 16, 0, 0);
#else
  int lane = threadIdx.x & 63;
  *(f16x8*)&lds[lane * 8] = *(const f16x8*)g;
#endif
}

// ---------------------------- convert kernels ------------------------------

__global__ void conv_logits(const float* __restrict__ src, f16* __restrict__ dst) {
  int idx = blockIdx.x * 256 + threadIdx.x;      // < 65536*128
  int row = idx >> 7, k = idx & 127;
  dst[idx] = (f16)((k < 120) ? src[(size_t)row * 120 + k] : 0.f);
}

__global__ void conv_wt0(const float* __restrict__ w, f16* __restrict__ dst) {
  int idx = blockIdx.x * 256 + threadIdx.x;      // < 2560*128
  int n = idx >> 7, k = idx & 127;
  dst[idx] = (f16)((k < 120) ? w[(size_t)n * 120 + k] : 0.f);
}

__global__ void conv_copy(const float* __restrict__ src, f16* __restrict__ dst, int count) {
  int idx = blockIdx.x * 256 + threadIdx.x;
  if (idx < count) dst[idx] = (f16)src[idx];
}

__global__ void conv_wtl(const float* __restrict__ w, f16* __restrict__ dst) {
  int idx = blockIdx.x * 256 + threadIdx.x;      // < 128*640
  int n = idx / 640, k = idx % 640;
  dst[idx] = (f16)((n < 72) ? w[(size_t)n * 640 + k] : 0.f);
}

// Whh -> group/half-aware packed layout for the 3-phase scan.
// For buffer (slot=layer*2+dir, half): thread tid in [0,512):
//   group = tid>>8 (0=A own-half k, 1=B partner-half k); gtid = tid&255
//   ksub = gtid&1 (80-wide);  task i in [0,5): local row lr = i*128+(gtid>>1)
//   gate = lr/160, u = lr%160 -> global row r = gate*320 + half*160 + u
//   khalf = group ? 1-half : half;  k = khalf*160 + ksub*80 + 2j, j in [0,40)
__global__ void conv_whh(const float* __restrict__ whh0, const float* __restrict__ whh,
                         uint32_t* __restrict__ dst) {
  int o = blockIdx.x * 256 + threadIdx.x;        // < 12*5*40*512 = 1228800
  int tid = o & 511;
  int g  = o >> 9;
  int j  = g % 40;
  int g2 = g / 40;
  int i  = g2 % 5;
  int g3 = g2 / 5;                               // 0..11
  int half = g3 & 1, slot = g3 >> 1;             // slot = layer*2+dir
  int group = tid >> 8, gtid = tid & 255;
  int ksub = gtid & 1;
  int lr = i * 128 + (gtid >> 1);
  int gate = lr / 160, u = lr - gate * 160;
  int r = gate * 320 + half * 160 + u;
  int khalf = group ? (1 - half) : half;
  int k = khalf * 160 + ksub * 80 + 2 * j;
  const float* srcm = (slot < 2) ? (whh0 + ((size_t)slot * 1280 + r) * 320)
                                 : (whh  + ((size_t)(slot - 2) * 1280 + r) * 320);
  f16 lo = (f16)srcm[k], hi = (f16)srcm[k + 1];
  dst[o] = (uint32_t)__builtin_bit_cast(unsigned short, lo) |
           ((uint32_t)__builtin_bit_cast(unsigned short, hi) << 16);
}

// --------------------- gather-GEMM for one time chunk ----------------------
__global__ __launch_bounds__(256)
void gemm_chunk(const f16* __restrict__ A, const f16* __restrict__ W,
                f16* __restrict__ gxc, const int* __restrict__ lens,
                int lda, int kTiles, int c0) {
  __shared__ __align__(16) f16 As[128 * 32];
  __shared__ __align__(16) f16 Ws[128 * 32];
  const int tid = threadIdx.x;
  const int lane = tid & 63, wid = tid >> 6;
  const int wm = wid >> 1, wn = wid & 1;
  const int dir = blockIdx.y >> 6, b = blockIdx.y & 63;
  const int n0 = blockIdx.x * 128;
  const int r_base = lane >> 2;
  const int c8 = (lane & 3) * 8;
  const int len = lens[b];

  f32x4 acc[4][4] = {};

  for (int kt = 0; kt < kTiles; ++kt) {
    const int k0 = kt * 32;
    __syncthreads();
#pragma unroll
    for (int hh = 0; hh < 2; ++hh) {
      const int c = wid * 2 + hh;
      const int j = c * 16 + r_base;                     // step within chunk
      const int s = c0 * CT + j;
      const int tt = dir ? ((s < len) ? (len - 1 - s) : s) : s;
      const f16* gA = A + (size_t)(b * 1024 + tt) * lda + k0 + c8;
      const f16* gW = W + (size_t)(dir * 1280 + n0 + c * 16 + r_base) * lda + k0 + c8;
      stage16(&As[c * 512], gA);
      stage16(&Ws[c * 512], gW);
    }
    __syncthreads();

    const int koff = (lane >> 4) * 8;
    f16x8 av[4], wv[4];
#pragma unroll
    for (int i = 0; i < 4; ++i)
      av[i] = *(const f16x8*)&As[(wm * 64 + i * 16 + (lane & 15)) * 32 + koff];
#pragma unroll
    for (int i = 0; i < 4; ++i)
      wv[i] = *(const f16x8*)&Ws[(wn * 64 + i * 16 + (lane & 15)) * 32 + koff];
#pragma unroll
    for (int i = 0; i < 4; ++i)
#pragma unroll
      for (int j = 0; j < 4; ++j)
        acc[i][j] = __builtin_amdgcn_mfma_f32_16x16x32_f16(av[i], wv[j], acc[i][j], 0, 0, 0);
  }

  const int r0 = (lane >> 4) * 4, cn = lane & 15;
  const size_t obase = (size_t)(dir * 64 + b) * CT;
#pragma unroll
  for (int i = 0; i < 4; ++i) {
    const int m = wm * 64 + i * 16 + r0;
#pragma unroll
    for (int j = 0; j < 4; ++j) {
      const int n = n0 + wn * 64 + j * 16 + cn;
#pragma unroll
      for (int r = 0; r < 4; ++r)
        gxc[(obase + m + r) * 1280 + n] = (f16)acc[i][j][r];
    }
  }
}

// ------------------------- LSTM scan (one chunk) ---------------------------
__global__ __launch_bounds__(512, 2)
void lstm_scan_chunk(const uint32_t* __restrict__ wbuf,
                     const f16* __restrict__ gxc,      // [2*64*CT][1280]
                     const float* __restrict__ bias,   // [2][1280] this layer
                     const int* __restrict__ lens,
                     f16* __restrict__ xnext,          // [65536][640]
                     u64* __restrict__ xq,             // [512][80] tagged u64
                     f16* __restrict__ hsave,          // [128][320]
                     float* __restrict__ csave,        // [256][160]
                     int layer, int c0) {
  const int wg = blockIdx.x;
  const int half = wg >> 7;
  const int bd = wg & 127;
  const int b = bd >> 1, dir = bd & 1;
  const int tid = threadIdx.x;
  const int group = tid >> 8, gtid = tid & 255;

  __shared__ __align__(16) f16 hbuf[320];
  __shared__ float yldsA[640];
  __shared__ float yldsB[640];
  __shared__ __align__(16) f16 hstage[64 * 160];   // 20 KB ring (steps & 63)

  // weights: 5 tasks x 40 packed-pair words
  h2v w[5][40];
  {
    const uint32_t* wb = wbuf + (size_t)((layer * 2 + dir) * 2 + half) * 200 * 512;
#pragma unroll
    for (int i = 0; i < 5; ++i)
#pragma unroll
      for (int j = 0; j < 40; ++j)
        w[i][j] = __builtin_bit_cast(h2v, wb[(i * 40 + j) * 512 + tid]);
  }

  const int len = lens[b];
  const int gu = half * 160 + tid;               // valid when tid<160
  const int khalf = group ? (1 - half) : half;
  const int kb2 = khalf * 80 + (gtid & 1) * 40;  // h2 base index for this thread
  const int lrb = gtid >> 1;                     // local-row base (rows i*128+lrb)

  if (tid < 160) {
    hbuf[gu] = (c0 == 0) ? (f16)0.f : hsave[bd * 320 + gu];
  }
  float c_state = 0.f;
  float bi = 0.f, bff = 0.f, bg = 0.f, bo = 0.f;
  if (tid < 160) {
    if (c0 > 0) c_state = csave[wg * 160 + tid];
    const float* bp = bias + dir * 1280 + gu;
    bi = bp[0]; bff = bp[320]; bg = bp[640]; bo = bp[960];
  }
  __syncthreads();

  const size_t grow0 = (size_t)(dir * 64 + b) * CT;
  u64* const my_xq   = xq + ((size_t)(bd * 2 + half) * 2) * 80;
  u64* const par_xq  = xq + ((size_t)(bd * 2 + (1 - half)) * 2) * 80;

  for (int tl = 0; tl < CT; ++tl) {
    const int s = c0 * CT + tl;
    const uint32_t tag = (uint32_t)(layer * 1024 + s + 1);

    // ================= PHASE 1 =================
    // publishers: send h[s-1] own half (2 values per u64 word)
    if (tid < 80) {
      const uint32_t lo = ((uint32_t)tag << 16) |
          (uint32_t)__builtin_bit_cast(unsigned short, hbuf[half * 160 + tid]);
      const uint32_t hi = ((uint32_t)tag << 16) |
          (uint32_t)__builtin_bit_cast(unsigned short, hbuf[half * 160 + 80 + tid]);
      const u64 word = ((u64)hi << 32) | (u64)lo;
      __hip_atomic_exchange(&my_xq[(s & 1) * 80 + tid], word,
                            __ATOMIC_RELAXED, __HIP_MEMORY_SCOPE_AGENT);
    }
    // gx prefetch for this step's gates (consumed after B3)
    float gxi = 0.f, gxf = 0.f, gxg = 0.f, gxo = 0.f;
    if (tid < 160) {
      const f16* gp = gxc + (grow0 + tl) * 1280 + gu;
      gxi = (float)gp[0]; gxf = (float)gp[320]; gxg = (float)gp[640]; gxo = (float)gp[960];
    }

    float acc0 = 0.f, acc1 = 0.f, acc2 = 0.f, acc3 = 0.f, acc4 = 0.f;
    const h2v* h2 = (const h2v*)hbuf;

    if (group == 0) {
      // A: dot over own-half k (h[s-1] own already in hbuf)
#pragma unroll
      for (int jb = 0; jb < 5; ++jb) {
        h2v hr[8];
#pragma unroll
        for (int j = 0; j < 8; ++j) hr[j] = h2[kb2 + jb * 8 + j];
#pragma unroll
        for (int j = 0; j < 8; ++j) {
          acc0 = dot2f(w[0][jb * 8 + j], hr[j], acc0);
          acc1 = dot2f(w[1][jb * 8 + j], hr[j], acc1);
          acc2 = dot2f(w[2][jb * 8 + j], hr[j], acc2);
          acc3 = dot2f(w[3][jb * 8 + j], hr[j], acc3);
          acc4 = dot2f(w[4][jb * 8 + j], hr[j], acc4);
        }
      }
      {
        float av[5] = {acc0, acc1, acc2, acc3, acc4};
#pragma unroll
        for (int i = 0; i < 5; ++i) {
          float v = av[i] + __shfl_xor(av[i], 1, 64);
          if (!(tid & 1)) yldsA[i * 128 + lrb] = v;
        }
      }
    } else if (gtid < 80) {
      // B pollers: receive partner h[s-1]
      u64 pw;
      int spins = 0;
      do {
        pw = __hip_atomic_fetch_add(&par_xq[(s & 1) * 80 + gtid], (u64)0,
                                    __ATOMIC_RELAXED, __HIP_MEMORY_SCOPE_AGENT);
      } while ((((uint32_t)(pw >> 48) != tag) ||
                ((uint32_t)((pw >> 16) & 0xffffu) != tag)) && ++spins < 200000);
      hbuf[(1 - half) * 160 + gtid] =
          __builtin_bit_cast(f16, (unsigned short)(pw & 0xffffu));
      hbuf[(1 - half) * 160 + 80 + gtid] =
          __builtin_bit_cast(f16, (unsigned short)((pw >> 32) & 0xffffu));
    }
    __syncthreads();   // B2: yldsA ready; partner h in hbuf

    // ================= PHASE 2 =================
    if (group == 1) {
      // B: dot over partner-half k
#pragma unroll
      for (int jb = 0; jb < 5; ++jb) {
        h2v hr[8];
#pragma unroll
        for (int j = 0; j < 8; ++j) hr[j] = h2[kb2 + jb * 8 + j];
#pragma unroll
        for (int j = 0; j < 8; ++j) {
          acc0 = dot2f(w[0][jb * 8 + j], hr[j], acc0);
          acc1 = dot2f(w[1][jb * 8 + j], hr[j], acc1);
          acc2 = dot2f(w[2][jb * 8 + j], hr[j], acc2);
          acc3 = dot2f(w[3][jb * 8 + j], hr[j], acc3);
          acc4 = dot2f(w[4][jb * 8 + j], hr[j], acc4);
        }
      }
      {
        float av[5] = {acc0, acc1, acc2, acc3, acc4};
#pragma unroll
        for (int i = 0; i < 5; ++i) {
          float v = av[i] + __shfl_xor(av[i], 1, 64);
          if (!(tid & 1)) yldsB[i * 128 + lrb] = v;
        }
      }
    } else if ((tl & 31) == 0 && tl > 0) {
      // A: flush previous 32-step window of h to xnext (coalesced 16B stores)
      const int tw = tl - 32;
#pragma unroll
      for (int it = 0; it < 3; ++it) {
        const int slot = it * 256 + tid;
        if (slot < 640) {
          const int r = (int)(((unsigned)slot * 52429u) >> 20);  // slot/20
          const int j = slot - r * 20;
          const int sp = c0 * CT + tw + r;
          const int ttp = dir ? ((sp < len) ? (len - 1 - sp) : sp) : sp;
          f16x8 v = *(const f16x8*)&hstage[((tw + r) & 63) * 160 + j * 8];
          *(f16x8*)&xnext[(size_t)(b * 1024 + ttp) * 640 + dir * 320 + half * 160 + j * 8] = v;
        }
      }
    }
    __syncthreads();   // B3: yldsB ready

    // ================= PHASE 3: gates =================
    if (tid < 160) {
      const int u = tid;
      float pi = yldsA[u]       + yldsB[u]       + gxi + bi;
      float pf = yldsA[160 + u] + yldsB[160 + u] + gxf + bff;
      float pg = yldsA[320 + u] + yldsB[320 + u] + gxg + bg;
      float po = yldsA[480 + u] + yldsB[480 + u] + gxo + bo;
      float ig = 1.f / (1.f + __expf(-pi));
      float fg = 1.f / (1.f + __expf(-pf));
      float gg = tanhf(pg);
      float og = 1.f / (1.f + __expf(-po));
      c_state = fg * c_state + ig * gg;
      float hv = og * tanhf(c_state);
      const f16 hh = (f16)hv;
      hbuf[gu] = hh;
      hstage[(tl & 63) * 160 + u] = hh;
    }
    __syncthreads();   // B1 (next): hbuf own ready for publish + A-dot
  }

  // final flush of last 32-step window
  {
    const int tw = CT - 32;
#pragma unroll
    for (int it = 0; it < 6; ++it) {
      const int slot = it * 512 + tid;
      if (slot < 640) {
        const int r = (int)(((unsigned)slot * 52429u) >> 20);
        const int j = slot - r * 20;
        const int sp = c0 * CT + tw + r;
        const int ttp = dir ? ((sp < len) ? (len - 1 - sp) : sp) : sp;
        f16x8 v = *(const f16x8*)&hstage[((tw + r) & 63) * 160 + j * 8];
        *(f16x8*)&xnext[(size_t)(b * 1024 + ttp) * 640 + dir * 320 + half * 160 + j * 8] = v;
      }
    }
  }
  // persist state for next chunk
  if (tid < 160) {
    hsave[bd * 320 + gu] = hbuf[gu];
    csave[wg * 160 + tid] = c_state;
  }
}

// ---------------------- projection GEMM (f32 out) --------------------------
__global__ __launch_bounds__(256)
void gemm_proj(const f16* __restrict__ A, const f16* __restrict__ W,
               float* __restrict__ outf, int lda, int kTiles, int ldo) {
  __shared__ __align__(16) f16 As[128 * 32];
  __shared__ __align__(16) f16 Ws[128 * 32];
  const int tid = threadIdx.x;
  const int lane = tid & 63, wid = tid >> 6;
  const int wm = wid >> 1, wn = wid & 1;
  const int m0 = blockIdx.y * 128, n0 = blockIdx.x * 128;
  const int r_base = lane >> 2;
  const int c8 = (lane & 3) * 8;

  f32x4 acc[4][4] = {};

  for (int kt = 0; kt < kTiles; ++kt) {
    const int k0 = kt * 32;
    __syncthreads();
#pragma unroll
    for (int hh = 0; hh < 2; ++hh) {
      const int c = wid * 2 + hh;
      const f16* gA = A + (size_t)(m0 + c * 16 + r_base) * lda + k0 + c8;
      const f16* gW = W + (size_t)(n0 + c * 16 + r_base) * lda + k0 + c8;
      stage16(&As[c * 512], gA);
      stage16(&Ws[c * 512], gW);
    }
    __syncthreads();

    const int koff = (lane >> 4) * 8;
    f16x8 av[4], wv[4];
#pragma unroll
    for (int i = 0; i < 4; ++i)
      av[i] = *(const f16x8*)&As[(wm * 64 + i * 16 + (lane & 15)) * 32 + koff];
#pragma unroll
    for (int i = 0; i < 4; ++i)
      wv[i] = *(const f16x8*)&Ws[(wn * 64 + i * 16 + (lane & 15)) * 32 + koff];
#pragma unroll
    for (int i = 0; i < 4; ++i)
#pragma unroll
      for (int j = 0; j < 4; ++j)
        acc[i][j] = __builtin_amdgcn_mfma_f32_16x16x32_f16(av[i], wv[j], acc[i][j], 0, 0, 0);
  }

  const int r0 = (lane >> 4) * 4, cn = lane & 15;
#pragma unroll
  for (int i = 0; i < 4; ++i) {
    const int m = m0 + wm * 64 + i * 16 + r0;
#pragma unroll
    for (int j = 0; j < 4; ++j) {
      const int n = n0 + wn * 64 + j * 16 + cn;
#pragma unroll
      for (int r = 0; r < 4; ++r)
        outf[(size_t)(m + r) * ldo + n] = acc[i][j][r];
    }
  }
}

// ------------------------- logsumexp over K=72 ------------------------------
__global__ void lse_kernel(const float* __restrict__ Z, const float* __restrict__ b_lin,
                           float* __restrict__ lseout) {
  int row = blockIdx.x * 4 + (threadIdx.x >> 6);
  int l = threadIdx.x & 63;
  const float* z = Z + (size_t)row * 128;
  float v0 = (l < 72) ? z[l] + b_lin[l] : NEGF;
  float v1 = (l < 8) ? z[l + 64] + b_lin[l + 64] : NEGF;
  float m = fmaxf(v0, v1);
#pragma unroll
  for (int o = 32; o; o >>= 1) m = fmaxf(m, __shfl_xor(m, o, 64));
  float s = ((l < 72) ? __expf(v0 - m) : 0.f) + ((l < 8) ? __expf(v1 - m) : 0.f);
#pragma unroll
  for (int o = 32; o; o >>= 1) s += __shfl_xor(s, o, 64);
  if (l == 0) lseout[row] = m + __logf(s);
}

// ------------------------------ CTC forward ---------------------------------
// One wave per batch. Lane l holds s = 4l..4l+3 (S=193 -> lanes 0..48).
// Neighbors via shfl_up; em prefetched 2 steps ahead; no barriers in t-loop.
__global__ void ctc_kernel(const float* __restrict__ Z, const float* __restrict__ lse,
                           const float* __restrict__ b_lin,
                           const int* __restrict__ labels, const int* __restrict__ inlen,
                           const int* __restrict__ lablen, float* __restrict__ num) {
  const int b = blockIdx.x;
  const int lane = threadIdx.x;          // 64
  __shared__ int ext[200];
  __shared__ float afin[200];

  for (int s = lane; s < 200; s += 64)
    ext[s] = (s < 193 && (s & 1)) ? labels[b * 96 + (s >> 1)] : 0;
  __syncthreads();

  const int L = lablen[b], len = inlen[b];
  const int Send = 2 * L + 1;
  const float* Zb = Z + (size_t)b * 1024 * 128;
  const float* lsb = lse + (size_t)b * 1024;

  float a[4];
  int   e[4];
  float bl[4];
  bool  skp[4], val[4];
#pragma unroll
  for (int j = 0; j < 4; ++j) {
    const int s = lane * 4 + j;
    e[j]   = (s < 193) ? ext[s] : 0;
    val[j] = (s < Send) && (s < 193);
    skp[j] = (s < 193) && (s & 1) && (s >= 2) && (ext[s] != ext[s - 2]);
    bl[j]  = b_lin[e[j]];
  }
  {
    const float ls0 = lsb[0];
#pragma unroll
    for (int j = 0; j < 4; ++j) {
      const int s = lane * 4 + j;
      a[j] = (s <= 1 && val[j]) ? (Zb[e[j]] + bl[j] - ls0) : NEGF;
    }
  }

  // depth-2 prefetch pipeline for em
  float emA[4], emB[4], lsA, lsB;
#pragma unroll
  for (int j = 0; j < 4; ++j) emA[j] = Zb[128 + e[j]];
  lsA = lsb[1];
#pragma unroll
  for (int j = 0; j < 4; ++j) emB[j] = Zb[256 + e[j]];
  lsB = lsb[2];

  for (int t = 1; t < len; ++t) {
    float em[4];
#pragma unroll
    for (int j = 0; j < 4; ++j) em[j] = emA[j];
    const float lst = lsA;
#pragma unroll
    for (int j = 0; j < 4; ++j) emA[j] = emB[j];
    lsA = lsB;
    if (t + 2 < len) {
      const float* zr = Zb + (size_t)(t + 2) * 128;
#pragma unroll
      for (int j = 0; j < 4; ++j) emB[j] = zr[e[j]];
      lsB = lsb[t + 2];
    }

    float p3 = __shfl_up(a[3], 1, 64);
    float p2 = __shfl_up(a[2], 1, 64);
    if (lane == 0) { p3 = NEGF; p2 = NEGF; }
    const float x2[4] = {p3, a[0], a[1], a[2]};
    const float x3[4] = {p2, p3, a[0], a[1]};
#pragma unroll
    for (int j = 0; j < 4; ++j) {
      const float xa = a[j], xb = x2[j];
      const float xc = skp[j] ? x3[j] : NEGF;
      const float m = fmaxf(xa, fmaxf(xb, xc));
      const float sum = __expf(xa - m) + __expf(xb - m) + __expf(xc - m);
      const float nv = m + __logf(sum) + em[j] + bl[j] - lst;
      a[j] = val[j] ? nv : NEGF;
    }
  }

#pragma unroll
  for (int j = 0; j < 4; ++j) {
    const int s = lane * 4 + j;
    if (s < 193) afin[s] = a[j];
  }
  __syncthreads();
  if (lane == 0) {
    const float aL = afin[2 * L], aLm1 = afin[2 * L - 1];
    const float m = fmaxf(aL, aLm1);
    num[b] = m + __logf(__expf(aL - m) + __expf(aLm1 - m));
  }
}

__global__ void final_kernel(const float* __restrict__ num, float* __restrict__ out) {
  int l = threadIdx.x;  // 64
  float v = -1.1f * num[l];
#pragma unroll
  for (int o = 32; o; o >>= 1) v += __shfl_xor(v, o, 64);
  if (l == 0) out[0] = v * (1.f / 64.f);
}

__global__ void sentinel_kernel(float* __restrict__ out, float code) { out[0] = code; }

// ------------------------------ launcher ------------------------------------
extern "C" void kernel_launch(void* const* d_in, const int* in_sizes, int n_in,
                              void* d_out, int out_size, void* d_ws, size_t ws_size,
                              hipStream_t stream) {
  (void)in_sizes; (void)n_in; (void)out_size;

  const float* logits   = (const float*)d_in[0];
  const int*   labels   = (const int*)d_in[1];
  const int*   in_lens  = (const int*)d_in[2];
  const int*   lab_lens = (const int*)d_in[3];
  const float* Wih0     = (const float*)d_in[4];
  const float* Whh0     = (const float*)d_in[5];
  const float* b0       = (const float*)d_in[6];
  const float* Wih      = (const float*)d_in[7];
  const float* Whh      = (const float*)d_in[8];
  const float* bb       = (const float*)d_in[9];
  const float* W_lin    = (const float*)d_in[10];
  const float* b_lin    = (const float*)d_in[11];

  const size_t NEED = (size_t)224 * 1024 * 1024;
  if (ws_size < NEED) {
    sentinel_kernel<<<1, 1, 0, stream>>>((float*)d_out, -(float)(ws_size >> 20));
    return;
  }

  char* ws = (char*)d_ws;
  size_t off = 0;
  auto alloc = [&](size_t bytes) -> char* {
    char* p = ws + off;
    off += (bytes + 255) & ~(size_t)255;
    return p;
  };
  f16*      Xa     = (f16*)alloc((size_t)65536 * 640 * 2);        // 83.9 MB
  f16*      Xb     = (f16*)alloc((size_t)65536 * 640 * 2);        // 83.9 MB
  f16*      gxc    = (f16*)alloc((size_t)2 * 64 * CT * 1280 * 2); // 41.9 MB
  f16*      Wt0    = (f16*)alloc((size_t)2560 * 128 * 2);
  f16*      Wt12   = (f16*)alloc((size_t)2 * 2560 * 640 * 2);
  f16*      WtL    = (f16*)alloc((size_t)128 * 640 * 2);
  uint32_t* whh16  = (uint32_t*)alloc((size_t)12 * 5 * 40 * 512 * 4);
  float*    lseb   = (float*)alloc((size_t)65536 * 4);
  float*    num    = (float*)alloc(64 * 4);
  u64*      xq     = (u64*)alloc((size_t)512 * 80 * 8);
  f16*      hsave  = (f16*)alloc((size_t)128 * 320 * 2);
  float*    csave  = (float*)alloc((size_t)256 * 160 * 4);
  // aliases (disjoint lifetimes)
  f16*      A0     = Xb;           // dead after layer 0; Xb first written layer 1
  float*    Z      = (float*)gxc;  // gxc dead after layer-2 scan

  hipMemsetAsync(xq, 0, (size_t)512 * 80 * 8, stream);

  conv_logits<<<32768, 256, 0, stream>>>(logits, A0);
  conv_wt0<<<1280, 256, 0, stream>>>(Wih0, Wt0);
  conv_copy<<<12800, 256, 0, stream>>>(Wih, Wt12, 3276800);
  conv_wtl<<<320, 256, 0, stream>>>(W_lin, WtL);
  conv_whh<<<4800, 256, 0, stream>>>(Whh0, Whh, whh16);

  // layer 0: A0 -> Xa
  for (int c = 0; c < 1024 / CT; ++c) {
    gemm_chunk<<<dim3(10, 128), 256, 0, stream>>>(A0, Wt0, gxc, in_lens, 128, 4, c);
    lstm_scan_chunk<<<256, 512, 0, stream>>>(whh16, gxc, b0, in_lens, Xa, xq,
                                             hsave, csave, 0, c);
  }
  // layer 1: Xa -> Xb
  for (int c = 0; c < 1024 / CT; ++c) {
    gemm_chunk<<<dim3(10, 128), 256, 0, stream>>>(Xa, Wt12, gxc, in_lens, 640, 20, c);
    lstm_scan_chunk<<<256, 512, 0, stream>>>(whh16, gxc, bb, in_lens, Xb, xq,
                                             hsave, csave, 1, c);
  }
  // layer 2: Xb -> Xa
  for (int c = 0; c < 1024 / CT; ++c) {
    gemm_chunk<<<dim3(10, 128), 256, 0, stream>>>(Xb, Wt12 + (size_t)2560 * 640, gxc,
                                                  in_lens, 640, 20, c);
    lstm_scan_chunk<<<256, 512, 0, stream>>>(whh16, gxc, bb + 2560, in_lens, Xa, xq,
                                             hsave, csave, 2, c);
  }
  // projection: Xa -> Z (f32)
  gemm_proj<<<dim3(1, 512), 256, 0, stream>>>(Xa, WtL, Z, 640, 20, 128);

  lse_kernel<<<16384, 256, 0, stream>>>(Z, b_lin, lseb);
  ctc_kernel<<<64, 64, 0, stream>>>(Z, lseb, b_lin, labels, in_lens, lab_lens, num);
  final_kernel<<<1, 64, 0, stream>>>(num, (float*)d_out);
}

// Round 6
// 9034.168 us; speedup vs baseline: 1.3323x; 1.3323x over previous
//
#include <hip/hip_runtime.h>
#include <cstdint>
#include <cstddef>

// ---------------------------------------------------------------------------
// CTC-CRF BLSTM pipeline for MI355X.  B=64 T=1024 IDIM=120 HDIM=320 K=72
// den == 0 analytically; batch sort is a no-op under the batch mean. Skipped.
//
// R6: R4 scan structure (all 512 threads dot in parallel, 4-way k-split,
// tagged u32 exchange) + FORCED weight residency:
//   - amdgpu_waves_per_eu(2,2): 256-VGPR budget (R4/R5's VGPR_Count=128
//     proved w[5][40] was remat'd into the loop -> 400KB/WG/step from L2
//     -> 3us/step L2-BW bound; this is the R4/R5 bottleneck)
//   - volatile weight loads (remat illegal) + non-restrict stores (reload
//     alias-illegal)
// Plus: ds_read_b128 hbuf reads, hstage ring -> coalesced xnext flush
// every 32 steps, one-wave CTC.
// ---------------------------------------------------------------------------

typedef _Float16 f16;
typedef _Float16 h2v   __attribute__((ext_vector_type(2)));
typedef _Float16 f16x8 __attribute__((ext_vector_type(8)));
typedef float    f32x4 __attribute__((ext_vector_type(4)));
typedef uint32_t u32x4 __attribute__((ext_vector_type(4)));

#define NEGF (-1e30f)
#define CT 128

__device__ __forceinline__ float dot2f(h2v a, h2v b, float c) {
#if __has_builtin(__builtin_amdgcn_fdot2)
  return __builtin_amdgcn_fdot2(a, b, c, false);
#else
  return c + (float)a.x * (float)b.x + (float)a.y * (float)b.y;
#endif
}

__device__ __forceinline__ void stage16(f16* lds, const f16* g) {
#if __has_builtin(__builtin_amdgcn_global_load_lds)
  __builtin_amdgcn_global_load_lds(
      (const __attribute__((address_space(1))) uint32_t*)g,
      (__attribute__((address_space(3))) uint32_t*)lds, 16, 0, 0);
#else
  int lane = threadIdx.x & 63;
  *(f16x8*)&lds[lane * 8] = *(const f16x8*)g;
#endif
}

// ---------------------------- convert kernels ------------------------------

__global__ void conv_logits(const float* __restrict__ src, f16* __restrict__ dst) {
  int idx = blockIdx.x * 256 + threadIdx.x;      // < 65536*128
  int row = idx >> 7, k = idx & 127;
  dst[idx] = (f16)((k < 120) ? src[(size_t)row * 120 + k] : 0.f);
}

__global__ void conv_wt0(const float* __restrict__ w, f16* __restrict__ dst) {
  int idx = blockIdx.x * 256 + threadIdx.x;      // < 2560*128
  int n = idx >> 7, k = idx & 127;
  dst[idx] = (f16)((k < 120) ? w[(size_t)n * 120 + k] : 0.f);
}

__global__ void conv_copy(const float* __restrict__ src, f16* __restrict__ dst, int count) {
  int idx = blockIdx.x * 256 + threadIdx.x;
  if (idx < count) dst[idx] = (f16)src[idx];
}

__global__ void conv_wtl(const float* __restrict__ w, f16* __restrict__ dst) {
  int idx = blockIdx.x * 256 + threadIdx.x;      // < 128*640
  int n = idx / 640, k = idx % 640;
  dst[idx] = (f16)((n < 72) ? w[(size_t)n * 640 + k] : 0.f);
}

// Whh -> R4 pair-packed scan layout:
//   tau = i*512+tid; lr = tau>>2 (row i*128 + tid>>2); kq = tau&3
//   gate = lr/160, u = lr%160 -> r = gate*320 + half*160 + u; k = kq*80 + 2j
__global__ void conv_whh(const float* __restrict__ whh0, const float* __restrict__ whh,
                         uint32_t* __restrict__ dst) {
  int o = blockIdx.x * 256 + threadIdx.x;        // < 6*2*200*512 = 1228800
  int tid = o & 511;
  int g  = o >> 9;
  int j  = g % 40;
  int g2 = g / 40;
  int i  = g2 % 5;
  int g3 = g2 / 5;                               // 0..11
  int hf = g3 & 1, slot = g3 >> 1;               // slot = layer*2+dir
  int tau = i * 512 + tid;
  int lr = tau >> 2, kq = tau & 3;
  int gate = lr / 160, u = lr - gate * 160;
  int r = gate * 320 + hf * 160 + u;
  int k = kq * 80 + j * 2;
  const float* srcm = (slot < 2) ? (whh0 + ((size_t)slot * 1280 + r) * 320)
                                 : (whh  + ((size_t)(slot - 2) * 1280 + r) * 320);
  f16 lo = (f16)srcm[k], hi = (f16)srcm[k + 1];
  dst[o] = (uint32_t)__builtin_bit_cast(unsigned short, lo) |
           ((uint32_t)__builtin_bit_cast(unsigned short, hi) << 16);
}

// --------------------- gather-GEMM for one time chunk ----------------------
__global__ __launch_bounds__(256)
void gemm_chunk(const f16* __restrict__ A, const f16* __restrict__ W,
                f16* __restrict__ gxc, const int* __restrict__ lens,
                int lda, int kTiles, int c0) {
  __shared__ __align__(16) f16 As[128 * 32];
  __shared__ __align__(16) f16 Ws[128 * 32];
  const int tid = threadIdx.x;
  const int lane = tid & 63, wid = tid >> 6;
  const int wm = wid >> 1, wn = wid & 1;
  const int dir = blockIdx.y >> 6, b = blockIdx.y & 63;
  const int n0 = blockIdx.x * 128;
  const int r_base = lane >> 2;
  const int c8 = (lane & 3) * 8;
  const int len = lens[b];

  f32x4 acc[4][4] = {};

  for (int kt = 0; kt < kTiles; ++kt) {
    const int k0 = kt * 32;
    __syncthreads();
#pragma unroll
    for (int hh = 0; hh < 2; ++hh) {
      const int c = wid * 2 + hh;
      const int j = c * 16 + r_base;                     // step within chunk
      const int s = c0 * CT + j;
      const int tt = dir ? ((s < len) ? (len - 1 - s) : s) : s;
      const f16* gA = A + (size_t)(b * 1024 + tt) * lda + k0 + c8;
      const f16* gW = W + (size_t)(dir * 1280 + n0 + c * 16 + r_base) * lda + k0 + c8;
      stage16(&As[c * 512], gA);
      stage16(&Ws[c * 512], gW);
    }
    __syncthreads();

    const int koff = (lane >> 4) * 8;
    f16x8 av[4], wv[4];
#pragma unroll
    for (int i = 0; i < 4; ++i)
      av[i] = *(const f16x8*)&As[(wm * 64 + i * 16 + (lane & 15)) * 32 + koff];
#pragma unroll
    for (int i = 0; i < 4; ++i)
      wv[i] = *(const f16x8*)&Ws[(wn * 64 + i * 16 + (lane & 15)) * 32 + koff];
#pragma unroll
    for (int i = 0; i < 4; ++i)
#pragma unroll
      for (int j = 0; j < 4; ++j)
        acc[i][j] = __builtin_amdgcn_mfma_f32_16x16x32_f16(av[i], wv[j], acc[i][j], 0, 0, 0);
  }

  const int r0 = (lane >> 4) * 4, cn = lane & 15;
  const size_t obase = (size_t)(dir * 64 + b) * CT;
#pragma unroll
  for (int i = 0; i < 4; ++i) {
    const int m = wm * 64 + i * 16 + r0;
#pragma unroll
    for (int j = 0; j < 4; ++j) {
      const int n = n0 + wn * 64 + j * 16 + cn;
#pragma unroll
      for (int r = 0; r < 4; ++r)
        gxc[(obase + m + r) * 1280 + n] = (f16)acc[i][j][r];
    }
  }
}

// ------------------------- LSTM scan (one chunk) ---------------------------
// 256 WGs: wg = half*128 + (b*2+dir). Pair (wg, wg^128) = two 160-unit halves.
// Whh half (640x320 f16) register-resident: 200 h2v/thread, forced via
// waves_per_eu(2,2) + volatile loads + may-alias stores (no remat/reload).
// NOTE: 1 block/CU at 256 VGPRs; 256 WGs == 256 CUs co-resident; spins bounded.
__global__ void __launch_bounds__(512)
__attribute__((amdgpu_waves_per_eu(2, 2)))
lstm_scan_chunk(const volatile uint32_t* wbuf,      // NOT restrict: may alias
                const f16* __restrict__ gxc,        // [2*64*CT][1280]
                const float* __restrict__ bias,     // [2][1280] this layer
                const int* __restrict__ lens,
                f16* xnext,                         // [65536][640] (no restrict)
                uint32_t* xq,                       // [512][160] tagged words
                f16* hsave,                         // [128][320]
                float* csave,                       // [256][160]
                int layer, int c0) {
  const int wg = blockIdx.x;
  const int half = wg >> 7;
  const int bd = wg & 127;
  const int b = bd >> 1, dir = bd & 1;
  const int tid = threadIdx.x;

  __shared__ __align__(16) f16 hbuf[320];
  __shared__ float ylds[640];
  __shared__ __align__(16) f16 hstage[64 * 160];   // 20 KB ring

  // weights: 5 tasks x 40 packed-pair words -- MUST stay in registers
  h2v w[5][40];
  {
    const volatile uint32_t* wb =
        wbuf + (size_t)((layer * 2 + dir) * 2 + half) * 200 * 512;
#pragma unroll
    for (int i = 0; i < 5; ++i)
#pragma unroll
      for (int j = 0; j < 40; ++j) {
        uint32_t v = wb[(i * 40 + j) * 512 + tid];
        w[i][j] = __builtin_bit_cast(h2v, v);
      }
  }
  if (tid < 320) hbuf[tid] = (c0 == 0) ? (f16)0.f : hsave[bd * 320 + tid];

  const int len = lens[b];
  const int kq = tid & 3;
  const int qi = tid >> 2;
  const int gu = half * 160 + tid;               // valid when tid<160
  float c_state = 0.f;
  float bi = 0.f, bff = 0.f, bg = 0.f, bo = 0.f;
  if (tid < 160) {
    if (c0 > 0) c_state = csave[wg * 160 + tid];
    const float* bp = bias + dir * 1280 + gu;
    bi = bp[0]; bff = bp[320]; bg = bp[640]; bo = bp[960];
  }
  __syncthreads();

  const size_t grow0 = (size_t)(dir * 64 + b) * CT;

  for (int tl = 0; tl < CT; ++tl) {
    const int s = c0 * CT + tl;
    const uint32_t tag = (uint32_t)(layer * 1024 + s + 1);

    // gx prefetch for this step's gates (hides latency behind the dot)
    float gxi = 0.f, gxf = 0.f, gxg = 0.f, gxo = 0.f;
    if (tid < 160) {
      const f16* gp = gxc + (grow0 + tl) * 1280 + gu;
      gxi = (float)gp[0]; gxf = (float)gp[320]; gxg = (float)gp[640]; gxo = (float)gp[960];
    }

    // ---- y = Whh_half . h  (full 320-wide h, b128 LDS reads) ----
    float a0 = 0.f, a1 = 0.f, a2 = 0.f, a3 = 0.f, a4 = 0.f;
    {
      const u32x4* h4 = (const u32x4*)hbuf;      // 16B units (8 f16)
#pragma unroll
      for (int jb = 0; jb < 5; ++jb) {
        u32x4 p = h4[kq * 10 + jb * 2];
        u32x4 q = h4[kq * 10 + jb * 2 + 1];
        h2v hr[8];
#pragma unroll
        for (int j = 0; j < 4; ++j) hr[j] = __builtin_bit_cast(h2v, p[j]);
#pragma unroll
        for (int j = 0; j < 4; ++j) hr[4 + j] = __builtin_bit_cast(h2v, q[j]);
#pragma unroll
        for (int j = 0; j < 8; ++j) {
          a0 = dot2f(w[0][jb * 8 + j], hr[j], a0);
          a1 = dot2f(w[1][jb * 8 + j], hr[j], a1);
          a2 = dot2f(w[2][jb * 8 + j], hr[j], a2);
          a3 = dot2f(w[3][jb * 8 + j], hr[j], a3);
          a4 = dot2f(w[4][jb * 8 + j], hr[j], a4);
        }
      }
    }
    {
      float av[5] = {a0, a1, a2, a3, a4};
#pragma unroll
      for (int i = 0; i < 5; ++i) {
        float v = av[i];
        v += __shfl_xor(v, 1, 64);
        v += __shfl_xor(v, 2, 64);
        if (kq == 0) ylds[i * 128 + qi] = v;
      }
    }

    // every 32 steps: flush the completed window of h to xnext (coalesced)
    if ((tl & 31) == 0 && tl > 0) {
      const int tw = tl - 32;
#pragma unroll
      for (int it = 0; it < 2; ++it) {
        const int slot = it * 512 + tid;
        if (slot < 640) {
          const int r = (int)(((unsigned)slot * 52429u) >> 20);  // slot/20
          const int j = slot - r * 20;
          const int sp = c0 * CT + tw + r;
          const int ttp = dir ? ((sp < len) ? (len - 1 - sp) : sp) : sp;
          f16x8 v = *(const f16x8*)&hstage[((tw + r) & 63) * 160 + j * 8];
          *(f16x8*)&xnext[(size_t)(b * 1024 + ttp) * 640 + dir * 320 + half * 160 + j * 8] = v;
        }
      }
    }
    __syncthreads();                              // B1: ylds ready

    if (tid < 160) {
      const int u = tid;
      float pi = ylds[u]       + gxi + bi;
      float pf = ylds[160 + u] + gxf + bff;
      float pg = ylds[320 + u] + gxg + bg;
      float po = ylds[480 + u] + gxo + bo;
      float ig = 1.f / (1.f + __expf(-pi));
      float fg = 1.f / (1.f + __expf(-pf));
      float gg = tanhf(pg);
      float og = 1.f / (1.f + __expf(-po));
      c_state = fg * c_state + ig * gg;
      float hv = og * tanhf(c_state);
      const f16 hh = (f16)hv;
      // publish own value (tagged u32, RMW -> coherence point, no fences)
      const uint32_t word = (tag << 16) |
                            (uint32_t)__builtin_bit_cast(unsigned short, hh);
      __hip_atomic_exchange(&xq[((bd * 2 + half) * 2 + (s & 1)) * 160 + u], word,
                            __ATOMIC_RELAXED, __HIP_MEMORY_SCOPE_AGENT);
      hbuf[gu] = hh;
      hstage[(tl & 63) * 160 + u] = hh;
      // poll partner's tagged word (bounded)
      uint32_t pw;
      int spins = 0;
      do {
        pw = __hip_atomic_fetch_add(&xq[((bd * 2 + (1 - half)) * 2 + (s & 1)) * 160 + u],
                                    0u, __ATOMIC_RELAXED, __HIP_MEMORY_SCOPE_AGENT);
      } while ((pw >> 16) != tag && ++spins < 30000);
      hbuf[(1 - half) * 160 + u] =
          __builtin_bit_cast(f16, (unsigned short)(pw & 0xffffu));
    }
    __syncthreads();                              // B2: hbuf ready for next dot
  }

  // final flush of last 32-step window
  {
    const int tw = CT - 32;
#pragma unroll
    for (int it = 0; it < 2; ++it) {
      const int slot = it * 512 + tid;
      if (slot < 640) {
        const int r = (int)(((unsigned)slot * 52429u) >> 20);
        const int j = slot - r * 20;
        const int sp = c0 * CT + tw + r;
        const int ttp = dir ? ((sp < len) ? (len - 1 - sp) : sp) : sp;
        f16x8 v = *(const f16x8*)&hstage[((tw + r) & 63) * 160 + j * 8];
        *(f16x8*)&xnext[(size_t)(b * 1024 + ttp) * 640 + dir * 320 + half * 160 + j * 8] = v;
      }
    }
  }
  // persist state for next chunk
  if (tid < 160) {
    hsave[bd * 320 + gu] = hbuf[gu];
    csave[wg * 160 + tid] = c_state;
  }
}

// ---------------------- projection GEMM (f32 out) --------------------------
__global__ __launch_bounds__(256)
void gemm_proj(const f16* __restrict__ A, const f16* __restrict__ W,
               float* __restrict__ outf, int lda, int kTiles, int ldo) {
  __shared__ __align__(16) f16 As[128 * 32];
  __shared__ __align__(16) f16 Ws[128 * 32];
  const int tid = threadIdx.x;
  const int lane = tid & 63, wid = tid >> 6;
  const int wm = wid >> 1, wn = wid & 1;
  const int m0 = blockIdx.y * 128, n0 = blockIdx.x * 128;
  const int r_base = lane >> 2;
  const int c8 = (lane & 3) * 8;

  f32x4 acc[4][4] = {};

  for (int kt = 0; kt < kTiles; ++kt) {
    const int k0 = kt * 32;
    __syncthreads();
#pragma unroll
    for (int hh = 0; hh < 2; ++hh) {
      const int c = wid * 2 + hh;
      const f16* gA = A + (size_t)(m0 + c * 16 + r_base) * lda + k0 + c8;
      const f16* gW = W + (size_t)(n0 + c * 16 + r_base) * lda + k0 + c8;
      stage16(&As[c * 512], gA);
      stage16(&Ws[c * 512], gW);
    }
    __syncthreads();

    const int koff = (lane >> 4) * 8;
    f16x8 av[4], wv[4];
#pragma unroll
    for (int i = 0; i < 4; ++i)
      av[i] = *(const f16x8*)&As[(wm * 64 + i * 16 + (lane & 15)) * 32 + koff];
#pragma unroll
    for (int i = 0; i < 4; ++i)
      wv[i] = *(const f16x8*)&Ws[(wn * 64 + i * 16 + (lane & 15)) * 32 + koff];
#pragma unroll
    for (int i = 0; i < 4; ++i)
#pragma unroll
      for (int j = 0; j < 4; ++j)
        acc[i][j] = __builtin_amdgcn_mfma_f32_16x16x32_f16(av[i], wv[j], acc[i][j], 0, 0, 0);
  }

  const int r0 = (lane >> 4) * 4, cn = lane & 15;
#pragma unroll
  for (int i = 0; i < 4; ++i) {
    const int m = m0 + wm * 64 + i * 16 + r0;
#pragma unroll
    for (int j = 0; j < 4; ++j) {
      const int n = n0 + wn * 64 + j * 16 + cn;
#pragma unroll
      for (int r = 0; r < 4; ++r)
        outf[(size_t)(m + r) * ldo + n] = acc[i][j][r];
    }
  }
}

// ------------------------- logsumexp over K=72 ------------------------------
__global__ void lse_kernel(const float* __restrict__ Z, const float* __restrict__ b_lin,
                           float* __restrict__ lseout) {
  int row = blockIdx.x * 4 + (threadIdx.x >> 6);
  int l = threadIdx.x & 63;
  const float* z = Z + (size_t)row * 128;
  float v0 = (l < 72) ? z[l] + b_lin[l] : NEGF;
  float v1 = (l < 8) ? z[l + 64] + b_lin[l + 64] : NEGF;
  float m = fmaxf(v0, v1);
#pragma unroll
  for (int o = 32; o; o >>= 1) m = fmaxf(m, __shfl_xor(m, o, 64));
  float s = ((l < 72) ? __expf(v0 - m) : 0.f) + ((l < 8) ? __expf(v1 - m) : 0.f);
#pragma unroll
  for (int o = 32; o; o >>= 1) s += __shfl_xor(s, o, 64);
  if (l == 0) lseout[row] = m + __logf(s);
}

// ------------------------------ CTC forward ---------------------------------
// One wave per batch. Lane l holds s = 4l..4l+3 (S=193 -> lanes 0..48).
__global__ void ctc_kernel(const float* __restrict__ Z, const float* __restrict__ lse,
                           const float* __restrict__ b_lin,
                           const int* __restrict__ labels, const int* __restrict__ inlen,
                           const int* __restrict__ lablen, float* __restrict__ num) {
  const int b = blockIdx.x;
  const int lane = threadIdx.x;          // 64
  __shared__ int ext[200];
  __shared__ float afin[200];

  for (int s = lane; s < 200; s += 64)
    ext[s] = (s < 193 && (s & 1)) ? labels[b * 96 + (s >> 1)] : 0;
  __syncthreads();

  const int L = lablen[b], len = inlen[b];
  const int Send = 2 * L + 1;
  const float* Zb = Z + (size_t)b * 1024 * 128;
  const float* lsb = lse + (size_t)b * 1024;

  float a[4];
  int   e[4];
  float bl[4];
  bool  skp[4], val[4];
#pragma unroll
  for (int j = 0; j < 4; ++j) {
    const int s = lane * 4 + j;
    e[j]   = (s < 193) ? ext[s] : 0;
    val[j] = (s < Send) && (s < 193);
    skp[j] = (s < 193) && (s & 1) && (s >= 2) && (ext[s] != ext[s - 2]);
    bl[j]  = b_lin[e[j]];
  }
  {
    const float ls0 = lsb[0];
#pragma unroll
    for (int j = 0; j < 4; ++j) {
      const int s = lane * 4 + j;
      a[j] = (s <= 1 && val[j]) ? (Zb[e[j]] + bl[j] - ls0) : NEGF;
    }
  }

  float emA[4], emB[4], lsA, lsB;
#pragma unroll
  for (int j = 0; j < 4; ++j) emA[j] = Zb[128 + e[j]];
  lsA = lsb[1];
#pragma unroll
  for (int j = 0; j < 4; ++j) emB[j] = Zb[256 + e[j]];
  lsB = lsb[2];

  for (int t = 1; t < len; ++t) {
    float em[4];
#pragma unroll
    for (int j = 0; j < 4; ++j) em[j] = emA[j];
    const float lst = lsA;
#pragma unroll
    for (int j = 0; j < 4; ++j) emA[j] = emB[j];
    lsA = lsB;
    if (t + 2 < len) {
      const float* zr = Zb + (size_t)(t + 2) * 128;
#pragma unroll
      for (int j = 0; j < 4; ++j) emB[j] = zr[e[j]];
      lsB = lsb[t + 2];
    }

    float p3 = __shfl_up(a[3], 1, 64);
    float p2 = __shfl_up(a[2], 1, 64);
    if (lane == 0) { p3 = NEGF; p2 = NEGF; }
    const float x2[4] = {p3, a[0], a[1], a[2]};
    const float x3[4] = {p2, p3, a[0], a[1]};
#pragma unroll
    for (int j = 0; j < 4; ++j) {
      const float xa = a[j], xb = x2[j];
      const float xc = skp[j] ? x3[j] : NEGF;
      const float m = fmaxf(xa, fmaxf(xb, xc));
      const float sum = __expf(xa - m) + __expf(xb - m) + __expf(xc - m);
      const float nv = m + __logf(sum) + em[j] + bl[j] - lst;
      a[j] = val[j] ? nv : NEGF;
    }
  }

#pragma unroll
  for (int j = 0; j < 4; ++j) {
    const int s = lane * 4 + j;
    if (s < 193) afin[s] = a[j];
  }
  __syncthreads();
  if (lane == 0) {
    const float aL = afin[2 * L], aLm1 = afin[2 * L - 1];
    const float m = fmaxf(aL, aLm1);
    num[b] = m + __logf(__expf(aL - m) + __expf(aLm1 - m));
  }
}

__global__ void final_kernel(const float* __restrict__ num, float* __restrict__ out) {
  int l = threadIdx.x;  // 64
  float v = -1.1f * num[l];
#pragma unroll
  for (int o = 32; o; o >>= 1) v += __shfl_xor(v, o, 64);
  if (l == 0) out[0] = v * (1.f / 64.f);
}

__global__ void sentinel_kernel(float* __restrict__ out, float code) { out[0] = code; }

// ------------------------------ launcher ------------------------------------
extern "C" void kernel_launch(void* const* d_in, const int* in_sizes, int n_in,
                              void* d_out, int out_size, void* d_ws, size_t ws_size,
                              hipStream_t stream) {
  (void)in_sizes; (void)n_in; (void)out_size;

  const float* logits   = (const float*)d_in[0];
  const int*   labels   = (const int*)d_in[1];
  const int*   in_lens  = (const int*)d_in[2];
  const int*   lab_lens = (const int*)d_in[3];
  const float* Wih0     = (const float*)d_in[4];
  const float* Whh0     = (const float*)d_in[5];
  const float* b0       = (const float*)d_in[6];
  const float* Wih      = (const float*)d_in[7];
  const float* Whh      = (const float*)d_in[8];
  const float* bb       = (const float*)d_in[9];
  const float* W_lin    = (const float*)d_in[10];
  const float* b_lin    = (const float*)d_in[11];

  const size_t NEED = (size_t)224 * 1024 * 1024;
  if (ws_size < NEED) {
    sentinel_kernel<<<1, 1, 0, stream>>>((float*)d_out, -(float)(ws_size >> 20));
    return;
  }

  char* ws = (char*)d_ws;
  size_t off = 0;
  auto alloc = [&](size_t bytes) -> char* {
    char* p = ws + off;
    off += (bytes + 255) & ~(size_t)255;
    return p;
  };
  f16*      Xa     = (f16*)alloc((size_t)65536 * 640 * 2);        // 83.9 MB
  f16*      Xb     = (f16*)alloc((size_t)65536 * 640 * 2);        // 83.9 MB
  f16*      gxc    = (f16*)alloc((size_t)2 * 64 * CT * 1280 * 2); // 41.9 MB
  f16*      Wt0    = (f16*)alloc((size_t)2560 * 128 * 2);
  f16*      Wt12   = (f16*)alloc((size_t)2 * 2560 * 640 * 2);
  f16*      WtL    = (f16*)alloc((size_t)128 * 640 * 2);
  uint32_t* whh16  = (uint32_t*)alloc((size_t)6 * 2 * 200 * 512 * 4);
  float*    lseb   = (float*)alloc((size_t)65536 * 4);
  float*    num    = (float*)alloc(64 * 4);
  uint32_t* xq     = (uint32_t*)alloc((size_t)512 * 160 * 4);
  f16*      hsave  = (f16*)alloc((size_t)128 * 320 * 2);
  float*    csave  = (float*)alloc((size_t)256 * 160 * 4);
  // aliases (disjoint lifetimes)
  f16*      A0     = Xb;           // dead after layer 0; Xb first written layer 1
  float*    Z      = (float*)gxc;  // gxc dead after layer-2 scan

  hipMemsetAsync(xq, 0, (size_t)512 * 160 * 4, stream);

  conv_logits<<<32768, 256, 0, stream>>>(logits, A0);
  conv_wt0<<<1280, 256, 0, stream>>>(Wih0, Wt0);
  conv_copy<<<12800, 256, 0, stream>>>(Wih, Wt12, 3276800);
  conv_wtl<<<320, 256, 0, stream>>>(W_lin, WtL);
  conv_whh<<<4800, 256, 0, stream>>>(Whh0, Whh, whh16);

  // layer 0: A0 -> Xa
  for (int c = 0; c < 1024 / CT; ++c) {
    gemm_chunk<<<dim3(10, 128), 256, 0, stream>>>(A0, Wt0, gxc, in_lens, 128, 4, c);
    lstm_scan_chunk<<<256, 512, 0, stream>>>(whh16, gxc, b0, in_lens, Xa, xq,
                                             hsave, csave, 0, c);
  }
  // layer 1: Xa -> Xb
  for (int c = 0; c < 1024 / CT; ++c) {
    gemm_chunk<<<dim3(10, 128), 256, 0, stream>>>(Xa, Wt12, gxc, in_lens, 640, 20, c);
    lstm_scan_chunk<<<256, 512, 0, stream>>>(whh16, gxc, bb, in_lens, Xb, xq,
                                             hsave, csave, 1, c);
  }
  // layer 2: Xb -> Xa
  for (int c = 0; c < 1024 / CT; ++c) {
    gemm_chunk<<<dim3(10, 128), 256, 0, stream>>>(Xb, Wt12 + (size_t)2560 * 640, gxc,
                                                  in_lens, 640, 20, c);
    lstm_scan_chunk<<<256, 512, 0, stream>>>(whh16, gxc, bb + 2560, in_lens, Xa, xq,
                                             hsave, csave, 2, c);
  }
  // projection: Xa -> Z (f32)
  gemm_proj<<<dim3(1, 512), 256, 0, stream>>>(Xa, WtL, Z, 640, 20, 128);

  lse_kernel<<<16384, 256, 0, stream>>>(Z, b_lin, lseb);
  ctc_kernel<<<64, 64, 0, stream>>>(Z, lseb, b_lin, labels, in_lens, lab_lens, num);
  final_kernel<<<1, 64, 0, stream>>>(num, (float*)d_out);
}